// Round 2
// baseline (2618.785 us; speedup 1.0000x reference)
//
#include <hip/hip_runtime.h>
#include <hip/hip_bf16.h>
#include <cstdint>

#define NT 256
#define N_ATOMS_C 600000
#define BATCH_C 24000

constexpr int K_COUNTS[11] = {10000,130000,170000,160000,100000,15000,5000,2500,2500,2500,2500};
constexpr int K_STARTS[11] = {0,10000,140000,310000,470000,570000,585000,590000,592500,595000,597500};

struct AdjPtrs { const int* p[10]; };

__device__ __forceinline__ float selu_f(float x) {
    const float scale = 1.0507009873554805f;
    const float alpha = 1.6732632423543772f;
    return scale * (x > 0.f ? x : alpha * expm1f(x));
}

// ---------------------------------------------------------------------------
// Conv layer: thread = target atom. rel[FIN] accumulated in registers
// (fully unrolled -> static indices -> stays in VGPRs). Weights read with
// wave-uniform addresses -> s_load -> SGPR operand in v_fma. No LDS, no
// barriers: occupancy + outstanding loads hide gather latency.
// FUSE_GATHER: last layer feeds segment sum/max atomics directly.
// ---------------------------------------------------------------------------
template<int FIN, int FO, bool FUSE_GATHER>
__global__ __launch_bounds__(256) void conv_kernel(
    const float* __restrict__ x,      // (N_ATOMS, FIN)
    const float* __restrict__ W,      // (21, FIN, FO)
    const float* __restrict__ bias,   // (21, FO)
    AdjPtrs adjp,
    float* __restrict__ y,            // (N_ATOMS, FO)  [unused if FUSE_GATHER]
    const int* __restrict__ mem,      // (N_ATOMS)      [only if FUSE_GATHER]
    float* __restrict__ sums,         // (BATCH, FO)    [only if FUSE_GATHER]
    unsigned* __restrict__ maxs)      // (BATCH, FO)    [only if FUSE_GATHER]
{
    // block -> (degree, tile): compile-time table, wave-uniform
    int blk = blockIdx.x;
    int deg = 0, s = 0, cnt = 0;
#pragma unroll
    for (int d = 0; d < 11; ++d) {
        const int nb = (K_COUNTS[d] + NT - 1) / NT;
        if (blk < nb) { deg = d; s = K_STARTS[d]; cnt = K_COUNTS[d]; break; }
        blk -= nb;
    }
    const int a = blk * NT + threadIdx.x;   // index within degree segment
    if (a >= cnt) return;
    const int atom = s + a;

    const float *Wa, *Wb, *ba, *bb;
    if (deg == 0) {
        Wb = W + 20 * FIN * FO; bb = bias + 20 * FO; Wa = Wb; ba = bb;
    } else {
        Wa = W + (2 * (deg - 1)) * FIN * FO; ba = bias + (2 * (deg - 1)) * FO;
        Wb = W + (2 * deg - 1) * FIN * FO;   bb = bias + (2 * deg - 1) * FO;
    }

    float acc[FO];
#pragma unroll
    for (int o = 0; o < FO; ++o) acc[o] = (deg > 0) ? (ba[o] + bb[o]) : bb[o];

    float r[FIN];

    // ---- self path: row load (75 sequential dwords) then matmul vs Wb ----
    {
        const float* xr = x + atom * FIN;
#pragma unroll
        for (int f = 0; f < FIN; ++f) r[f] = xr[f];
#pragma unroll
        for (int f = 0; f < FIN; ++f) {
            const float v = r[f];
#pragma unroll
            for (int o = 0; o < FO; ++o) acc[o] += v * Wb[f * FO + o];
        }
    }

    // ---- neighbor path: accumulate rel in regs, then matmul vs Wa ----
    if (deg > 0) {
        const int* myadj = adjp.p[deg - 1] + a * deg;
#pragma unroll
        for (int f = 0; f < FIN; ++f) r[f] = 0.f;
        for (int k = 0; k < deg; ++k) {
            const float* xr = x + myadj[k] * FIN;
#pragma unroll
            for (int f = 0; f < FIN; ++f) r[f] += xr[f];
        }
#pragma unroll
        for (int f = 0; f < FIN; ++f) {
            const float v = r[f];
#pragma unroll
            for (int o = 0; o < FO; ++o) acc[o] += v * Wa[f * FO + o];
        }
    }

    if (!FUSE_GATHER) {
        float* yp = y + atom * FO;
#pragma unroll
        for (int o = 0; o < FO; ++o) yp[o] = selu_f(acc[o]);
    } else {
        const int m = mem[atom];
#pragma unroll
        for (int o = 0; o < FO; ++o) {
            const float v = selu_f(acc[o]);
            atomicAdd(&sums[m * FO + o], v);
            const unsigned bits = __float_as_uint(v);
            const unsigned enc = bits ^ ((bits >> 31) ? 0xFFFFFFFFu : 0x80000000u);
            atomicMax(&maxs[m * FO + o], enc);
        }
    }
}

// ---------------------------------------------------------------------------
__global__ __launch_bounds__(256) void init_kernel(float* __restrict__ sums,
                                                   unsigned* __restrict__ maxs)
{
    const int i = blockIdx.x * NT + threadIdx.x;
    if (i < BATCH_C * 36) { sums[i] = 0.f; maxs[i] = 0x007FFFFFu; } // enc(-inf)
}

// ---------------------------------------------------------------------------
// mol = tanh([sums, decode(maxs)]); logits = mol @ Wd + bd; softmax pairs
// ---------------------------------------------------------------------------
__global__ __launch_bounds__(256) void dense_kernel(
    const float* __restrict__ sums, const unsigned* __restrict__ maxs,
    const float* __restrict__ Wd,   // (72, 24)
    const float* __restrict__ bd,   // (24)
    float* __restrict__ out)        // (BATCH, 12, 2)
{
    __shared__ float sW[72 * 24];
    __shared__ float sb[24];
    __shared__ float sMol[64][72];

    const int tid = threadIdx.x;
    for (int i = tid; i < 72 * 24; i += NT) sW[i] = Wd[i];
    if (tid < 24) sb[tid] = bd[tid];

    const int m0 = blockIdx.x * 64;
    for (int i = tid; i < 64 * 36; i += NT) {
        const int j = i / 36, f = i - j * 36;
        const int m = m0 + j;
        if (m < BATCH_C) {
            sMol[j][f] = tanhf(sums[m * 36 + f]);
            const unsigned enc = maxs[m * 36 + f];
            const unsigned bits = (enc & 0x80000000u) ? (enc ^ 0x80000000u) : ~enc;
            sMol[j][36 + f] = tanhf(__uint_as_float(bits));
        }
    }
    __syncthreads();

    for (int i = tid; i < 64 * 12; i += NT) {
        const int j = i / 12, t = i - j * 12;
        const int m = m0 + j;
        if (m >= BATCH_C) continue;
        float l0 = sb[2 * t], l1 = sb[2 * t + 1];
#pragma unroll
        for (int f = 0; f < 72; ++f) {
            const float v = sMol[j][f];
            l0 += v * sW[f * 24 + 2 * t];
            l1 += v * sW[f * 24 + 2 * t + 1];
        }
        const float mx = fmaxf(l0, l1);
        const float e0 = expf(l0 - mx), e1 = expf(l1 - mx);
        const float inv = 1.f / (e0 + e1);
        out[m * 24 + 2 * t]     = e0 * inv;
        out[m * 24 + 2 * t + 1] = e1 * inv;
    }
}

// ---------------------------------------------------------------------------
extern "C" void kernel_launch(void* const* d_in, const int* in_sizes, int n_in,
                              void* d_out, int out_size, void* d_ws, size_t ws_size,
                              hipStream_t stream)
{
    const float* x0         = (const float*)d_in[0];
    const int*   membership = (const int*)d_in[2];
    AdjPtrs adj;
    for (int d = 0; d < 10; ++d) adj.p[d] = (const int*)d_in[3 + d];
    const float *W1=(const float*)d_in[13], *b1=(const float*)d_in[14];
    const float *W2=(const float*)d_in[15], *b2=(const float*)d_in[16];
    const float *W3=(const float*)d_in[17], *b3=(const float*)d_in[18];
    const float *W4=(const float*)d_in[19], *b4=(const float*)d_in[20];
    const float *Wd=(const float*)d_in[21], *bd=(const float*)d_in[22];

    // workspace: bufA 600000*27, bufB 600000*20, sums 24000*36, maxs 24000*36
    const size_t needA = (size_t)N_ATOMS_C * 27, needB = (size_t)N_ATOMS_C * 20;
    const size_t needBytes = (needA + needB + 2ull * BATCH_C * 36) * 4ull;
    if (ws_size < needBytes) return;

    float* bufA = (float*)d_ws;
    float* bufB = bufA + needA;
    float* sums = bufB + needB;
    unsigned* maxs = (unsigned*)(sums + BATCH_C * 36);

    int nblk = 0;
    for (int d = 0; d < 11; ++d) nblk += (K_COUNTS[d] + NT - 1) / NT;

    init_kernel<<<(BATCH_C * 36 + NT - 1) / NT, NT, 0, stream>>>(sums, maxs);

    conv_kernel<75,15,false><<<nblk, NT, 0, stream>>>(x0,  W1, b1, adj, bufA, nullptr, nullptr, nullptr);
    conv_kernel<15,20,false><<<nblk, NT, 0, stream>>>(bufA, W2, b2, adj, bufB, nullptr, nullptr, nullptr);
    conv_kernel<20,27,false><<<nblk, NT, 0, stream>>>(bufB, W3, b3, adj, bufA, nullptr, nullptr, nullptr);
    conv_kernel<27,36,true ><<<nblk, NT, 0, stream>>>(bufA, W4, b4, adj, nullptr, membership, sums, maxs);

    dense_kernel<<<(BATCH_C + 63) / 64, NT, 0, stream>>>(sums, maxs, Wd, bd, (float*)d_out);
}